// Round 5
// baseline (365.151 us; speedup 1.0000x reference)
//
#include <hip/hip_runtime.h>
#include <hip/hip_bf16.h>
#include <stdint.h>

#define M_TOT 8192
#define N_TOT 4096
#define K_TOT 4096
#define BM 256
#define BN 256
#define BK 64
#define NT (K_TOT / BK)   // 64 K-tiles

typedef short s16x8 __attribute__((ext_vector_type(8)));
typedef float f32x4 __attribute__((ext_vector_type(4)));

// fp32 -> bf16 round-to-nearest-even
__device__ __forceinline__ short f2bf(float f) {
    unsigned int u = __float_as_uint(f);
    u = (u + 0x7fffu + ((u >> 16) & 1u)) >> 16;
    return (short)u;
}

__device__ __forceinline__ void async_copy16(const void* g, void* l) {
    __builtin_amdgcn_global_load_lds(
        (const __attribute__((address_space(1))) void*)g,
        (__attribute__((address_space(3))) void*)l, 16, 0, 0);
}

// ---------------- pass 1a: x fp32 -> bf16 ----------------
__global__ __launch_bounds__(256)
void cvt_x(const float* __restrict__ x, short* __restrict__ xbf, int n8) {
    const int idx = blockIdx.x * blockDim.x + threadIdx.x;
    const int stride = gridDim.x * blockDim.x;
    for (int i = idx; i < n8; i += stride) {
        const float4 f0 = ((const float4*)x)[(size_t)i * 2];
        const float4 f1 = ((const float4*)x)[(size_t)i * 2 + 1];
        s16x8 v;
        v[0] = f2bf(f0.x); v[1] = f2bf(f0.y); v[2] = f2bf(f0.z); v[3] = f2bf(f0.w);
        v[4] = f2bf(f1.x); v[5] = f2bf(f1.y); v[6] = f2bf(f1.z); v[7] = f2bf(f1.w);
        ((s16x8*)xbf)[i] = v;
    }
}

// ---------------- pass 1b: int4 -> bf16 W^T [OUT][IN], coalesced writes ----------------
__global__ __launch_bounds__(256)
void dequant_w(const int* __restrict__ qw, const float* __restrict__ scales,
               const float* __restrict__ zeros, short* __restrict__ wt) {
    __shared__ short tile[256 * 64];   // [o_local][k_local], 16B granules XOR-swizzled

    const int t  = threadIdx.x;
    const int o0 = blockIdx.x * 256;
    const int kb = blockIdx.y;         // 64-k block => 32 packed rows
    const int r0 = kb * 32;
    const int o  = o0 + t;
    const float c0 = scales[o];
    const float c1 = -rintf(zeros[o] / c0) * c0;

    #pragma unroll
    for (int j = 0; j < 8; ++j) {      // granule j = k_local [j*8, j*8+8)
        s16x8 v;
        #pragma unroll
        for (int i = 0; i < 4; ++i) {
            const int q = qw[(size_t)(r0 + j * 4 + i) * N_TOT + o];  // coalesced reads
            v[2 * i]     = f2bf(fmaf((float)(q & 15), c0, c1));
            v[2 * i + 1] = f2bf(fmaf((float)((q >> 4) & 15), c0, c1));
        }
        *(s16x8*)&tile[t * 64 + ((j ^ (t & 7)) << 3)] = v;
    }
    __syncthreads();

    // write out: lane group of 8 covers one row's 128B contiguously
    #pragma unroll
    for (int it = 0; it < 8; ++it) {
        const int L = it * 256 + t;
        const int row = L >> 3, gg = L & 7;
        *(s16x8*)&wt[(size_t)(o0 + row) * K_TOT + kb * 64 + gg * 8] =
            *(const s16x8*)&tile[row * 64 + ((gg ^ (row & 7)) << 3)];
    }
}

// ---------------- pass 2: 256^2 8-phase bf16 GEMM (snake order, vmcnt(6)) ----------------
__global__ __launch_bounds__(512, 2)
void gemm_bf16(const short* __restrict__ xbf, const short* __restrict__ wt,
               const float* __restrict__ bias, float* __restrict__ out) {
    __shared__ short As[2][BM * BK];   // 2 x 32 KiB
    __shared__ short Bs[2][BN * BK];   // 2 x 32 KiB  (W^T rows = output cols)

    const int tid  = threadIdx.x;
    const int bid  = blockIdx.x;
    // XCD-aware bijective swizzle (512 % 8 == 0)
    const int sw   = (bid & 7) * 64 + (bid >> 3);
    const int n0   = (sw >> 5) * BN;   // 16 n-blocks
    const int m0   = (sw & 31) * BM;   // 32 m-blocks
    const int lane = tid & 63;
    const int wid  = tid >> 6;         // 0..7
    const int wr   = wid >> 2;         // 0..1 (M)
    const int wc   = wid & 3;          // 0..3 (N)
    const int lrow = lane & 15;
    const int lk   = lane >> 4;
    const int gb0  = tid & 448;        // wave-aligned base of tid

    f32x4 acc[8][4] = {};
    s16x8 afr[4][2], bfr[2][2];

    // stage one A half-chunk (128 rows x 64 k = 16KB, 2 loads/thread)
    auto stageA = [&](int bb, int kt, int half) {
        const int k0 = (kt & (NT - 1)) * BK;
        #pragma unroll
        for (int j = 0; j < 2; ++j) {
            const int g  = j * 512 + tid;
            const int R  = ((g >> 3) & 63) + ((g >> 9) & 1) * 128 + half * 64;
            const int c  = g & 7;
            const int gb = j * 512 + gb0;
            const int Rb = ((gb >> 3) & 63) + ((gb >> 9) & 1) * 128 + half * 64;
            async_copy16(xbf + (size_t)(m0 + R) * K_TOT + k0 + ((c ^ (R & 7)) << 3),
                         &As[bb][Rb * 64]);
        }
    };
    auto stageB = [&](int bb, int kt, int half) {
        const int k0 = (kt & (NT - 1)) * BK;
        #pragma unroll
        for (int j = 0; j < 2; ++j) {
            const int g  = j * 512 + tid;
            const int R  = ((g >> 3) & 31) + ((g >> 8) & 3) * 64 + half * 32;
            const int c  = g & 7;
            const int gb = j * 512 + gb0;
            const int Rb = ((gb >> 3) & 31) + ((gb >> 8) & 3) * 64 + half * 32;
            async_copy16(wt + (size_t)(n0 + R) * K_TOT + k0 + ((c ^ (R & 7)) << 3),
                         &Bs[bb][Rb * 64]);
        }
    };

#define READ_A(BUF, MH)                                                          \
    _Pragma("unroll")                                                            \
    for (int mi = 0; mi < 4; ++mi) {                                             \
        const int row = wr * 128 + (MH) * 64 + mi * 16 + lrow;                   \
        _Pragma("unroll")                                                        \
        for (int ks = 0; ks < 2; ++ks) {                                         \
            const int gran = ks * 4 + lk;                                        \
            afr[mi][ks] = *(const s16x8*)&As[BUF][row * 64 + ((gran ^ (row & 7)) << 3)]; \
        }                                                                        \
    }

#define READ_B(BUF, NH)                                                          \
    _Pragma("unroll")                                                            \
    for (int ni = 0; ni < 2; ++ni) {                                             \
        const int row = wc * 64 + (NH) * 32 + ni * 16 + lrow;                    \
        _Pragma("unroll")                                                        \
        for (int ks = 0; ks < 2; ++ks) {                                         \
            const int gran = ks * 4 + lk;                                        \
            bfr[ni][ks] = *(const s16x8*)&Bs[BUF][row * 64 + ((gran ^ (row & 7)) << 3)]; \
        }                                                                        \
    }

#define PHASE(BUF, MH, NH, RA, RB, STAGE_STMT, VM)                               \
    {                                                                            \
        if (RA) { READ_A(BUF, MH); }                                             \
        if (RB) { READ_B(BUF, NH); }                                             \
        STAGE_STMT;                                                              \
        if (VM) asm volatile("s_waitcnt vmcnt(6)" ::: "memory");                 \
        __builtin_amdgcn_s_barrier();                                            \
        asm volatile("s_waitcnt lgkmcnt(0)" ::: "memory");                       \
        __builtin_amdgcn_s_setprio(1);                                           \
        _Pragma("unroll")                                                        \
        for (int ks = 0; ks < 2; ++ks)                                           \
            _Pragma("unroll")                                                    \
            for (int mi = 0; mi < 4; ++mi)                                       \
                _Pragma("unroll")                                                \
                for (int ni = 0; ni < 2; ++ni)                                   \
                    acc[(MH) * 4 + mi][(NH) * 2 + ni] =                          \
                        __builtin_amdgcn_mfma_f32_16x16x32_bf16(                 \
                            afr[mi][ks], bfr[ni][ks],                            \
                            acc[(MH) * 4 + mi][(NH) * 2 + ni], 0, 0, 0);         \
        __builtin_amdgcn_s_setprio(0);                                           \
        __builtin_amdgcn_s_barrier();                                            \
    }

    // prologue: tile0 (4 chunks) then tile1 {A h0, B h1, A h1} (3 chunks) = 14 loads
    stageA(0, 0, 0); stageB(0, 0, 0); stageA(0, 0, 1); stageB(0, 0, 1);
    stageA(1, 1, 0); stageB(1, 1, 1); stageA(1, 1, 1);
    asm volatile("s_waitcnt vmcnt(6)" ::: "memory");   // tile0 fully landed
    __builtin_amdgcn_s_barrier();

    // snake quads: (0,0)->(0,1)->(1,1)->(1,0); 1 chunk staged per phase;
    // vmcnt(6) at P3 (guards buf1 reads) and P7 (guards next buf0 reads).
    for (int i = 0; i < NT / 2; ++i) {
        const int t = 2 * i;
        PHASE(0, 0, 0, 1, 1, stageB(1, t + 1, 0), 0);
        PHASE(0, 0, 1, 0, 1, stageA(0, t + 2, 0), 0);
        PHASE(0, 1, 1, 1, 0, stageB(0, t + 2, 1), 0);
        PHASE(0, 1, 0, 0, 1, stageA(0, t + 2, 1), 1);
        PHASE(1, 0, 0, 1, 1, stageB(0, t + 2, 0), 0);
        PHASE(1, 0, 1, 0, 1, stageA(1, t + 3, 0), 0);
        PHASE(1, 1, 1, 1, 0, stageB(1, t + 3, 1), 0);
        PHASE(1, 1, 0, 0, 1, stageA(1, t + 3, 1), 1);
    }
    asm volatile("s_waitcnt vmcnt(0)" ::: "memory");   // drain wrapped strays

    // epilogue: C/D layout col = lane&15, row = (lane>>4)*4 + j
    #pragma unroll
    for (int mi8 = 0; mi8 < 8; ++mi8) {
        const int rg = m0 + wr * 128 + mi8 * 16 + lk * 4;
        #pragma unroll
        for (int ni4 = 0; ni4 < 4; ++ni4) {
            const int cg = n0 + wc * 64 + ni4 * 16 + lrow;
            const float bs = bias[cg];
            #pragma unroll
            for (int j = 0; j < 4; ++j)
                out[(size_t)(rg + j) * N_TOT + cg] = acc[mi8][ni4][j] + bs;
        }
    }
#undef PHASE
#undef READ_A
#undef READ_B
}

// ---------------- fallback: fused kernel (small ws) ----------------
__global__ __launch_bounds__(256, 2)
void qlin_fused(const float* __restrict__ x,
                const int* __restrict__ qw,
                const float* __restrict__ scales,
                const float* __restrict__ zeros,
                const float* __restrict__ bias,
                float* __restrict__ out) {
    __shared__ short As[128 * 64];
    __shared__ short Bs[128 * 64];

    const int tid = threadIdx.x;
    const int n0 = blockIdx.x * 128;
    const int m0 = blockIdx.y * 128;

    const int a_kg   = tid & 7;
    const int a_row0 = tid >> 3;
    const int b_oloc = tid & 127;
    const int b_rg0  = tid >> 7;

    const int ocol = n0 + b_oloc;
    const float c0 = scales[ocol];
    const float c1 = -rintf(zeros[ocol] / c0) * c0;

    const int lane = tid & 63;
    const int wv   = tid >> 6;
    const int wr   = wv >> 1;
    const int wc   = wv & 1;
    const int lrow = lane & 15;
    const int lk   = lane >> 4;

    f32x4 acc[4][4] = {};

    for (int kt = 0; kt < K_TOT / 64; ++kt) {
        const int k0 = kt * 64;
        {
            const float* srcb = x + (size_t)(m0)*K_TOT + k0 + a_kg * 8;
            #pragma unroll
            for (int i = 0; i < 4; ++i) {
                const int row = a_row0 + 32 * i;
                const float4 f0 = *(const float4*)(srcb + (size_t)row * K_TOT);
                const float4 f1 = *(const float4*)(srcb + (size_t)row * K_TOT + 4);
                s16x8 v;
                v[0] = f2bf(f0.x); v[1] = f2bf(f0.y); v[2] = f2bf(f0.z); v[3] = f2bf(f0.w);
                v[4] = f2bf(f1.x); v[5] = f2bf(f1.y); v[6] = f2bf(f1.z); v[7] = f2bf(f1.w);
                *(s16x8*)&As[row * 64 + ((a_kg ^ (row & 7)) << 3)] = v;
            }
        }
        {
            const int rbase = k0 >> 1;
            #pragma unroll
            for (int i = 0; i < 4; ++i) {
                const int rg = b_rg0 + 2 * i;
                const int* qp = qw + (size_t)(rbase + rg * 4) * N_TOT + ocol;
                s16x8 v;
                #pragma unroll
                for (int rr = 0; rr < 4; ++rr) {
                    const int q = qp[(size_t)rr * N_TOT];
                    v[2 * rr]     = f2bf(fmaf((float)(q & 15), c0, c1));
                    v[2 * rr + 1] = f2bf(fmaf((float)((q >> 4) & 15), c0, c1));
                }
                *(s16x8*)&Bs[b_oloc * 64 + ((rg ^ (b_oloc & 7)) << 3)] = v;
            }
        }
        __syncthreads();
        #pragma unroll
        for (int ks = 0; ks < 2; ++ks) {
            const int slot = ks * 4 + lk;
            s16x8 a[4], b[4];
            #pragma unroll
            for (int mi = 0; mi < 4; ++mi) {
                const int row = wr * 64 + mi * 16 + lrow;
                a[mi] = *(const s16x8*)&As[row * 64 + ((slot ^ (row & 7)) << 3)];
            }
            #pragma unroll
            for (int ni = 0; ni < 4; ++ni) {
                const int row = wc * 64 + ni * 16 + lrow;
                b[ni] = *(const s16x8*)&Bs[row * 64 + ((slot ^ (row & 7)) << 3)];
            }
            #pragma unroll
            for (int mi = 0; mi < 4; ++mi)
                #pragma unroll
                for (int ni = 0; ni < 4; ++ni)
                    acc[mi][ni] = __builtin_amdgcn_mfma_f32_16x16x32_bf16(
                        a[mi], b[ni], acc[mi][ni], 0, 0, 0);
        }
        __syncthreads();
    }

    #pragma unroll
    for (int mi = 0; mi < 4; ++mi) {
        const int rg = m0 + wr * 64 + mi * 16 + lk * 4;
        #pragma unroll
        for (int ni = 0; ni < 4; ++ni) {
            const int cg = n0 + wc * 64 + ni * 16 + lrow;
            const float bs = bias[cg];
            #pragma unroll
            for (int j = 0; j < 4; ++j)
                out[(size_t)(rg + j) * N_TOT + cg] = acc[mi][ni][j] + bs;
        }
    }
}

extern "C" void kernel_launch(void* const* d_in, const int* in_sizes, int n_in,
                              void* d_out, int out_size, void* d_ws, size_t ws_size,
                              hipStream_t stream) {
    const float* x      = (const float*)d_in[0];
    const int*   qw     = (const int*)d_in[1];
    const float* scales = (const float*)d_in[2];
    const float* zeros  = (const float*)d_in[3];
    const float* bias   = (const float*)d_in[4];
    float* out = (float*)d_out;

    const size_t XBF_BYTES = (size_t)M_TOT * K_TOT * 2;
    const size_t WT_BYTES  = (size_t)N_TOT * K_TOT * 2;

    if (ws_size >= XBF_BYTES + WT_BYTES) {
        short* xbf = (short*)d_ws;
        short* wt  = (short*)((char*)d_ws + XBF_BYTES);

        hipLaunchKernelGGL(cvt_x, dim3(2048), dim3(256), 0, stream,
                           x, xbf, (int)((size_t)M_TOT * K_TOT / 8));
        hipLaunchKernelGGL(dequant_w, dim3(N_TOT / 256, K_TOT / 64), dim3(256), 0, stream,
                           qw, scales, zeros, wt);
        hipLaunchKernelGGL(gemm_bf16, dim3((M_TOT / BM) * (N_TOT / BN)), dim3(512), 0, stream,
                           xbf, wt, bias, out);
    } else {
        hipLaunchKernelGGL(qlin_fused, dim3(N_TOT / 128, M_TOT / 128), dim3(256), 0, stream,
                           x, qw, scales, zeros, bias, out);
    }
}

// Round 6
// 287.174 us; speedup vs baseline: 1.2715x; 1.2715x over previous
//
#include <hip/hip_runtime.h>
#include <hip/hip_bf16.h>
#include <stdint.h>

#define M_TOT 8192
#define N_TOT 4096
#define K_TOT 4096
#define BM 128
#define BN 128
#define BK 64
#define NCVT 2048

typedef short s16x8 __attribute__((ext_vector_type(8)));
typedef float f32x4 __attribute__((ext_vector_type(4)));

// fp32 -> bf16 round-to-nearest-even
__device__ __forceinline__ short f2bf(float f) {
    unsigned int u = __float_as_uint(f);
    u = (u + 0x7fffu + ((u >> 16) & 1u)) >> 16;
    return (short)u;
}

__device__ __forceinline__ void async_copy16(const void* g, void* l) {
    __builtin_amdgcn_global_load_lds(
        (const __attribute__((address_space(1))) void*)g,
        (__attribute__((address_space(3))) void*)l, 16, 0, 0);
}

// ---------------- pass 1 (merged): x fp32->bf16  +  int4 -> bf16 W^T ----------------
__global__ __launch_bounds__(256)
void prep(const float* __restrict__ x, const int* __restrict__ qw,
          const float* __restrict__ scales, const float* __restrict__ zeros,
          short* __restrict__ xbf, short* __restrict__ wt) {
    __shared__ short tile[256 * 64];
    const int t = threadIdx.x;

    if (blockIdx.x < NCVT) {
        // ---- cvt role: x fp32 -> bf16, 8 elems/thread/iter ----
        const int n8 = (M_TOT / 8) * K_TOT / 1;  // number of 8-elem groups = M*K/8
        const int idx = blockIdx.x * 256 + t;
        const int stride = NCVT * 256;
        for (int i = idx; i < (M_TOT * (K_TOT / 8)); i += stride) {
            const float4 f0 = ((const float4*)x)[(size_t)i * 2];
            const float4 f1 = ((const float4*)x)[(size_t)i * 2 + 1];
            s16x8 v;
            v[0] = f2bf(f0.x); v[1] = f2bf(f0.y); v[2] = f2bf(f0.z); v[3] = f2bf(f0.w);
            v[4] = f2bf(f1.x); v[5] = f2bf(f1.y); v[6] = f2bf(f1.z); v[7] = f2bf(f1.w);
            ((s16x8*)xbf)[i] = v;
        }
        (void)n8;
    } else {
        // ---- dequant role: W^T [OUT][IN] bf16, coalesced via LDS transpose ----
        const int bq = blockIdx.x - NCVT;   // 0..1023
        const int o0 = (bq & 15) * 256;
        const int kb = bq >> 4;             // 64-k block => 32 packed rows
        const int r0 = kb * 32;
        const int o  = o0 + t;
        const float c0 = scales[o];
        const float c1 = -rintf(zeros[o] / c0) * c0;

        #pragma unroll
        for (int j = 0; j < 8; ++j) {       // granule j = k_local [j*8, j*8+8)
            s16x8 v;
            #pragma unroll
            for (int i = 0; i < 4; ++i) {
                const int q = qw[(size_t)(r0 + j * 4 + i) * N_TOT + o];  // coalesced
                v[2 * i]     = f2bf(fmaf((float)(q & 15), c0, c1));
                v[2 * i + 1] = f2bf(fmaf((float)((q >> 4) & 15), c0, c1));
            }
            *(s16x8*)&tile[t * 64 + ((j ^ (t & 7)) << 3)] = v;
        }
        __syncthreads();

        #pragma unroll
        for (int it = 0; it < 8; ++it) {
            const int L = it * 256 + t;
            const int row = L >> 3, gg = L & 7;
            *(s16x8*)&wt[(size_t)(o0 + row) * K_TOT + kb * 64 + gg * 8] =
                *(const s16x8*)&tile[row * 64 + ((gg ^ (row & 7)) << 3)];
        }
    }
}

// ---------------- pass 2: bf16 GEMM (r2 structure) + full-line epilogue ----------------
__global__ __launch_bounds__(256, 2)
void gemm_bf16(const short* __restrict__ xbf, const short* __restrict__ wt,
               const float* __restrict__ bias, float* __restrict__ out) {
    __shared__ short Sm[2 * BM * BK];       // As | Bs, 32 KiB total
    short* As = Sm;
    short* Bs = Sm + BM * BK;

    const int tid = threadIdx.x;
    const int n0 = blockIdx.x * BN;
    const int m0 = blockIdx.y * BM;
    const int lane = tid & 63;
    const int wv = tid >> 6;
    const int wr = wv >> 1, wc = wv & 1;
    const int lrow = lane & 15, lk = lane >> 4;

    f32x4 acc[4][4] = {};

    for (int kt = 0; kt < K_TOT / BK; ++kt) {
        const int k0 = kt * BK;
        // stage A: 1024 granules of 16B; LDS granule (row,c) <- global (row, c^(row&7))
        #pragma unroll
        for (int i = 0; i < 4; ++i) {
            const int g = i * 256 + wv * 64 + lane;
            const int row = g >> 3, c = g & 7;
            async_copy16(xbf + (size_t)(m0 + row) * K_TOT + k0 + ((c ^ (row & 7)) << 3),
                         &As[(i * 256 + wv * 64) * 8]);
        }
        #pragma unroll
        for (int i = 0; i < 4; ++i) {
            const int g = i * 256 + wv * 64 + lane;
            const int row = g >> 3, c = g & 7;
            async_copy16(wt + (size_t)(n0 + row) * K_TOT + k0 + ((c ^ (row & 7)) << 3),
                         &Bs[(i * 256 + wv * 64) * 8]);
        }
        __syncthreads();   // vmcnt(0) drain + barrier

        #pragma unroll
        for (int ks = 0; ks < 2; ++ks) {
            const int slot = ks * 4 + lk;
            s16x8 a[4], b[4];
            #pragma unroll
            for (int mi = 0; mi < 4; ++mi) {
                const int row = wr * 64 + mi * 16 + lrow;
                a[mi] = *(const s16x8*)&As[row * 64 + ((slot ^ (row & 7)) << 3)];
            }
            #pragma unroll
            for (int ni = 0; ni < 4; ++ni) {
                const int row = wc * 64 + ni * 16 + lrow;
                b[ni] = *(const s16x8*)&Bs[row * 64 + ((slot ^ (row & 7)) << 3)];
            }
            #pragma unroll
            for (int mi = 0; mi < 4; ++mi)
                #pragma unroll
                for (int ni = 0; ni < 4; ++ni)
                    acc[mi][ni] = __builtin_amdgcn_mfma_f32_16x16x32_bf16(
                        a[mi], b[ni], acc[mi][ni], 0, 0, 0);
        }
        __syncthreads();
    }

    // ---- epilogue: full-line stores via LDS transpose (bias folded) ----
    // reuse Sm as float buffer: 64 rows x 128 cols fp32 = 32 KiB per pass
    float* fbuf = (float*)Sm;
    #pragma unroll
    for (int p = 0; p < 2; ++p) {
        __syncthreads();   // previous LDS use (K-loop / prior pass reads) complete
        #pragma unroll
        for (int q = 0; q < 2; ++q) {       // mi = 2p + q
            const int mi = 2 * p + q;
            const int rl = wr * 32 + q * 16 + lk * 4;
            #pragma unroll
            for (int ni = 0; ni < 4; ++ni) {
                const int col = wc * 64 + ni * 16 + lrow;
                const float bs = bias[n0 + col];
                #pragma unroll
                for (int j = 0; j < 4; ++j) {
                    const int r = rl + j;
                    // XOR-swizzle (granule=4 floats): bank spread at 2-lane/bank minimum
                    fbuf[r * 128 + (col ^ (((r >> 2) & 1) << 4))] = acc[mi][ni][j] + bs;
                }
            }
        }
        __syncthreads();
        // store 64 rows x 128 cols: 8 rounds, each wave-instr writes 1KB contiguous
        #pragma unroll
        for (int rd = 0; rd < 8; ++rd) {
            const int L = rd * 256 + tid;
            const int r = L >> 5;            // 0..63
            const int c4 = (L & 31) * 4;     // col base (float4)
            const float4 v = *(const float4*)&fbuf[r * 128 + (c4 ^ (((r >> 2) & 1) << 4))];
            const int grow = m0 + (r >> 5) * 64 + p * 32 + (r & 31);
            *(float4*)&out[(size_t)grow * N_TOT + n0 + c4] = v;
        }
    }
}

// ---------------- fallback: fused kernel (small ws) ----------------
__global__ __launch_bounds__(256, 2)
void qlin_fused(const float* __restrict__ x,
                const int* __restrict__ qw,
                const float* __restrict__ scales,
                const float* __restrict__ zeros,
                const float* __restrict__ bias,
                float* __restrict__ out) {
    __shared__ short As[128 * 64];
    __shared__ short Bs[128 * 64];

    const int tid = threadIdx.x;
    const int n0 = blockIdx.x * 128;
    const int m0 = blockIdx.y * 128;

    const int a_kg   = tid & 7;
    const int a_row0 = tid >> 3;
    const int b_oloc = tid & 127;
    const int b_rg0  = tid >> 7;

    const int ocol = n0 + b_oloc;
    const float c0 = scales[ocol];
    const float c1 = -rintf(zeros[ocol] / c0) * c0;

    const int lane = tid & 63;
    const int wv   = tid >> 6;
    const int wr   = wv >> 1;
    const int wc   = wv & 1;
    const int lrow = lane & 15;
    const int lk   = lane >> 4;

    f32x4 acc[4][4] = {};

    for (int kt = 0; kt < K_TOT / 64; ++kt) {
        const int k0 = kt * 64;
        {
            const float* srcb = x + (size_t)(m0)*K_TOT + k0 + a_kg * 8;
            #pragma unroll
            for (int i = 0; i < 4; ++i) {
                const int row = a_row0 + 32 * i;
                const float4 f0 = *(const float4*)(srcb + (size_t)row * K_TOT);
                const float4 f1 = *(const float4*)(srcb + (size_t)row * K_TOT + 4);
                s16x8 v;
                v[0] = f2bf(f0.x); v[1] = f2bf(f0.y); v[2] = f2bf(f0.z); v[3] = f2bf(f0.w);
                v[4] = f2bf(f1.x); v[5] = f2bf(f1.y); v[6] = f2bf(f1.z); v[7] = f2bf(f1.w);
                *(s16x8*)&As[row * 64 + ((a_kg ^ (row & 7)) << 3)] = v;
            }
        }
        {
            const int rbase = k0 >> 1;
            #pragma unroll
            for (int i = 0; i < 4; ++i) {
                const int rg = b_rg0 + 2 * i;
                const int* qp = qw + (size_t)(rbase + rg * 4) * N_TOT + ocol;
                s16x8 v;
                #pragma unroll
                for (int rr = 0; rr < 4; ++rr) {
                    const int q = qp[(size_t)rr * N_TOT];
                    v[2 * rr]     = f2bf(fmaf((float)(q & 15), c0, c1));
                    v[2 * rr + 1] = f2bf(fmaf((float)((q >> 4) & 15), c0, c1));
                }
                *(s16x8*)&Bs[b_oloc * 64 + ((rg ^ (b_oloc & 7)) << 3)] = v;
            }
        }
        __syncthreads();
        #pragma unroll
        for (int ks = 0; ks < 2; ++ks) {
            const int slot = ks * 4 + lk;
            s16x8 a[4], b[4];
            #pragma unroll
            for (int mi = 0; mi < 4; ++mi) {
                const int row = wr * 64 + mi * 16 + lrow;
                a[mi] = *(const s16x8*)&As[row * 64 + ((slot ^ (row & 7)) << 3)];
            }
            #pragma unroll
            for (int ni = 0; ni < 4; ++ni) {
                const int row = wc * 64 + ni * 16 + lrow;
                b[ni] = *(const s16x8*)&Bs[row * 64 + ((slot ^ (row & 7)) << 3)];
            }
            #pragma unroll
            for (int mi = 0; mi < 4; ++mi)
                #pragma unroll
                for (int ni = 0; ni < 4; ++ni)
                    acc[mi][ni] = __builtin_amdgcn_mfma_f32_16x16x32_bf16(
                        a[mi], b[ni], acc[mi][ni], 0, 0, 0);
        }
        __syncthreads();
    }

    #pragma unroll
    for (int mi = 0; mi < 4; ++mi) {
        const int rg = m0 + wr * 64 + mi * 16 + lk * 4;
        #pragma unroll
        for (int ni = 0; ni < 4; ++ni) {
            const int cg = n0 + wc * 64 + ni * 16 + lrow;
            const float bs = bias[cg];
            #pragma unroll
            for (int j = 0; j < 4; ++j)
                out[(size_t)(rg + j) * N_TOT + cg] = acc[mi][ni][j] + bs;
        }
    }
}

extern "C" void kernel_launch(void* const* d_in, const int* in_sizes, int n_in,
                              void* d_out, int out_size, void* d_ws, size_t ws_size,
                              hipStream_t stream) {
    const float* x      = (const float*)d_in[0];
    const int*   qw     = (const int*)d_in[1];
    const float* scales = (const float*)d_in[2];
    const float* zeros  = (const float*)d_in[3];
    const float* bias   = (const float*)d_in[4];
    float* out = (float*)d_out;

    const size_t XBF_BYTES = (size_t)M_TOT * K_TOT * 2;
    const size_t WT_BYTES  = (size_t)N_TOT * K_TOT * 2;

    if (ws_size >= XBF_BYTES + WT_BYTES) {
        short* xbf = (short*)d_ws;
        short* wt  = (short*)((char*)d_ws + XBF_BYTES);

        hipLaunchKernelGGL(prep, dim3(NCVT + 1024), dim3(256), 0, stream,
                           x, qw, scales, zeros, xbf, wt);
        hipLaunchKernelGGL(gemm_bf16, dim3(N_TOT / BN, M_TOT / BM), dim3(256), 0, stream,
                           xbf, wt, bias, out);
    } else {
        hipLaunchKernelGGL(qlin_fused, dim3(N_TOT / 128, M_TOT / 128), dim3(256), 0, stream,
                           x, qw, scales, zeros, bias, out);
    }
}

// Round 7
// 173.735 us; speedup vs baseline: 2.1018x; 1.6529x over previous
//
#include <hip/hip_runtime.h>
#include <hip/hip_bf16.h>
#include <stdint.h>

#define M_TOT 8192
#define N_TOT 4096
#define K_TOT 4096
#define BM 128
#define BN 128
#define BKI 128              // int8 K-tile: 128 B rows -> r2's conflict-free swizzle
#define NTI (K_TOT / BKI)    // 32 tiles

typedef short s16x8 __attribute__((ext_vector_type(8)));
typedef float f32x4 __attribute__((ext_vector_type(4)));
typedef int   i32x4 __attribute__((ext_vector_type(4)));
typedef char  i8x16 __attribute__((ext_vector_type(16)));

// fp32 -> bf16 round-to-nearest-even (fallback path)
__device__ __forceinline__ short f2bf(float f) {
    unsigned int u = __float_as_uint(f);
    u = (u + 0x7fffu + ((u >> 16) & 1u)) >> 16;
    return (short)u;
}

__device__ __forceinline__ void async_copy16(const void* g, void* l) {
    __builtin_amdgcn_global_load_lds(
        (const __attribute__((address_space(1))) void*)g,
        (__attribute__((address_space(3))) void*)l, 16, 0, 0);
}

// ---------------- pass 1 (merged): quantize x -> int8 (per-row) + unpack W -> int8 W^T ----------------
__global__ __launch_bounds__(256)
void prep(const float* __restrict__ x, const int* __restrict__ qw,
          char* __restrict__ xq, char* __restrict__ wq,
          float* __restrict__ sxv, float* __restrict__ sumv) {
    __shared__ float rmax[4], rsum[4];
    __shared__ char tile[256 * 64];
    const int t = threadIdx.x;

    if (blockIdx.x < M_TOT) {
        // ---- per-row quantize: thread t owns 16 consecutive elems ----
        const int row = blockIdx.x;
        const float* xp = x + (size_t)row * K_TOT + t * 16;
        f32x4 f[4];
        float amax = 0.f, sum = 0.f;
        #pragma unroll
        for (int i = 0; i < 4; ++i) {
            f[i] = *(const f32x4*)(xp + i * 4);
            #pragma unroll
            for (int j = 0; j < 4; ++j) {
                amax = fmaxf(amax, fabsf(f[i][j]));
                sum += f[i][j];
            }
        }
        #pragma unroll
        for (int s = 1; s < 64; s <<= 1) {
            amax = fmaxf(amax, __shfl_xor(amax, s, 64));
            sum += __shfl_xor(sum, s, 64);
        }
        const int wv = t >> 6;
        if ((t & 63) == 0) { rmax[wv] = amax; rsum[wv] = sum; }
        __syncthreads();
        amax = fmaxf(fmaxf(rmax[0], rmax[1]), fmaxf(rmax[2], rmax[3]));
        sum  = rsum[0] + rsum[1] + rsum[2] + rsum[3];
        const float inv = amax > 0.f ? 127.0f / amax : 0.f;
        i8x16 v;
        #pragma unroll
        for (int i = 0; i < 4; ++i)
            #pragma unroll
            for (int j = 0; j < 4; ++j)
                v[i * 4 + j] = (char)(int)rintf(f[i][j] * inv);
        *(i8x16*)&xq[(size_t)row * K_TOT + t * 16] = v;
        if (t == 0) { sxv[row] = amax * (1.0f / 127.0f); sumv[row] = sum; }
    } else {
        // ---- W int4 -> int8, transposed to [OUT][IN] via LDS ----
        const int bq = blockIdx.x - M_TOT;     // 0..1023
        const int o0 = (bq & 15) * 256;
        const int kb = bq >> 4;                // 64-k block -> 32 packed rows
        const int r0 = kb * 32;
        const int o  = o0 + t;
        #pragma unroll
        for (int g = 0; g < 4; ++g) {          // granule g = 16 ks = 8 packed rows
            i8x16 v;
            #pragma unroll
            for (int p = 0; p < 8; ++p) {
                const int q = qw[(size_t)(r0 + g * 8 + p) * N_TOT + o];  // coalesced
                v[2 * p]     = (char)(q & 15);
                v[2 * p + 1] = (char)((q >> 4) & 15);
            }
            *(i8x16*)&tile[t * 64 + ((g ^ (t & 3)) << 4)] = v;
        }
        __syncthreads();
        #pragma unroll
        for (int it = 0; it < 4; ++it) {
            const int L = it * 256 + t;
            const int row = L >> 2, c = L & 3;
            *(i8x16*)&wq[(size_t)(o0 + row) * K_TOT + kb * 64 + c * 16] =
                *(const i8x16*)&tile[row * 64 + ((c ^ (row & 3)) << 4)];
        }
    }
}

// ---------------- pass 2: W4A8 int8 GEMM (r2 structure, BK=128 int8) ----------------
__global__ __launch_bounds__(256, 2)
void gemm_i8(const char* __restrict__ xq, const char* __restrict__ wq,
             const float* __restrict__ sxv, const float* __restrict__ sumv,
             const float* __restrict__ scales, const float* __restrict__ zeros,
             const float* __restrict__ bias, float* __restrict__ out) {
    __shared__ __align__(16) char Sm8[32768];   // As | Bs (16 KB each); reused as fp32 epilogue buf
    char* As = Sm8;
    char* Bs = Sm8 + 16384;

    const int tid = threadIdx.x;
    const int n0 = blockIdx.x * BN;
    const int m0 = blockIdx.y * BM;
    const int lane = tid & 63;
    const int wv = tid >> 6;
    const int wr = wv >> 1, wc = wv & 1;
    const int lrow = lane & 15, lk = lane >> 4;

    i32x4 acc[4][4] = {};

    for (int kt = 0; kt < NTI; ++kt) {
        const int k0 = kt * BKI;
        // stage A: 1024 granules of 16B (128 rows x 8); LDS (row,c) <- global (row, c^(row&7))
        #pragma unroll
        for (int i = 0; i < 4; ++i) {
            const int g = i * 256 + wv * 64 + lane;
            const int row = g >> 3, c = g & 7;
            async_copy16(xq + (size_t)(m0 + row) * K_TOT + k0 + ((c ^ (row & 7)) << 4),
                         &As[(i * 256 + wv * 64) * 16]);
        }
        #pragma unroll
        for (int i = 0; i < 4; ++i) {
            const int g = i * 256 + wv * 64 + lane;
            const int row = g >> 3, c = g & 7;
            async_copy16(wq + (size_t)(n0 + row) * K_TOT + k0 + ((c ^ (row & 7)) << 4),
                         &Bs[(i * 256 + wv * 64) * 16]);
        }
        __syncthreads();   // vmcnt(0) drain + barrier

        #pragma unroll
        for (int ks = 0; ks < 2; ++ks) {
            const int slot = ks * 4 + lk;      // granule (16 ks) within 128-B row
            i32x4 a[4], b[4];
            #pragma unroll
            for (int mi = 0; mi < 4; ++mi) {
                const int row = wr * 64 + mi * 16 + lrow;
                a[mi] = *(const i32x4*)&As[row * 128 + ((slot ^ (row & 7)) << 4)];
            }
            #pragma unroll
            for (int ni = 0; ni < 4; ++ni) {
                const int row = wc * 64 + ni * 16 + lrow;
                b[ni] = *(const i32x4*)&Bs[row * 128 + ((slot ^ (row & 7)) << 4)];
            }
            #pragma unroll
            for (int mi = 0; mi < 4; ++mi)
                #pragma unroll
                for (int ni = 0; ni < 4; ++ni)
                    acc[mi][ni] = __builtin_amdgcn_mfma_i32_16x16x64_i8(
                        a[mi], b[ni], acc[mi][ni], 0, 0, 0);
        }
        __syncthreads();
    }

    // ---- epilogue: y = c0*sx*S1 + c1*Sx + bias; full-line stores via LDS ----
    float* fbuf = (float*)Sm8;
    float c0v[4], c1v[4], bsv[4];
    #pragma unroll
    for (int ni = 0; ni < 4; ++ni) {
        const int cg = n0 + wc * 64 + ni * 16 + lrow;
        const float c0 = scales[cg];
        c0v[ni] = c0;
        c1v[ni] = -rintf(zeros[cg] / c0) * c0;
        bsv[ni] = bias[cg];
    }
    #pragma unroll
    for (int p = 0; p < 2; ++p) {
        __syncthreads();   // prior LDS readers done
        #pragma unroll
        for (int q = 0; q < 2; ++q) {          // mi = 2p + q
            const int mi = 2 * p + q;
            const int rl = wr * 32 + q * 16 + lk * 4;
            #pragma unroll
            for (int j = 0; j < 4; ++j) {
                const int r = rl + j;
                const int gr = m0 + wr * 64 + mi * 16 + lk * 4 + j;
                const float sx = sxv[gr];
                const float Sx = sumv[gr];
                #pragma unroll
                for (int ni = 0; ni < 4; ++ni) {
                    const int col = wc * 64 + ni * 16 + lrow;
                    const float y = fmaf(c0v[ni] * sx, (float)acc[mi][ni][j],
                                         fmaf(c1v[ni], Sx, bsv[ni]));
                    fbuf[r * 128 + (col ^ (((r >> 2) & 1) << 4))] = y;
                }
            }
        }
        __syncthreads();
        #pragma unroll
        for (int rd = 0; rd < 8; ++rd) {
            const int L = rd * 256 + tid;
            const int r = L >> 5;
            const int c4 = (L & 31) * 4;
            const float4 v = *(const float4*)&fbuf[r * 128 + (c4 ^ (((r >> 2) & 1) << 4))];
            const int grow = m0 + (r >> 5) * 64 + p * 32 + (r & 31);
            *(float4*)&out[(size_t)grow * N_TOT + n0 + c4] = v;
        }
    }
}

// ---------------- fallback: fused bf16 kernel (small ws) ----------------
__global__ __launch_bounds__(256, 2)
void qlin_fused(const float* __restrict__ x,
                const int* __restrict__ qw,
                const float* __restrict__ scales,
                const float* __restrict__ zeros,
                const float* __restrict__ bias,
                float* __restrict__ out) {
    __shared__ short As[128 * 64];
    __shared__ short Bs[128 * 64];

    const int tid = threadIdx.x;
    const int n0 = blockIdx.x * 128;
    const int m0 = blockIdx.y * 128;

    const int a_kg   = tid & 7;
    const int a_row0 = tid >> 3;
    const int b_oloc = tid & 127;
    const int b_rg0  = tid >> 7;

    const int ocol = n0 + b_oloc;
    const float c0 = scales[ocol];
    const float c1 = -rintf(zeros[ocol] / c0) * c0;

    const int lane = tid & 63;
    const int wv   = tid >> 6;
    const int wr   = wv >> 1;
    const int wc   = wv & 1;
    const int lrow = lane & 15;
    const int lk   = lane >> 4;

    f32x4 acc[4][4] = {};

    for (int kt = 0; kt < K_TOT / 64; ++kt) {
        const int k0 = kt * 64;
        {
            const float* srcb = x + (size_t)(m0)*K_TOT + k0 + a_kg * 8;
            #pragma unroll
            for (int i = 0; i < 4; ++i) {
                const int row = a_row0 + 32 * i;
                const float4 f0 = *(const float4*)(srcb + (size_t)row * K_TOT);
                const float4 f1 = *(const float4*)(srcb + (size_t)row * K_TOT + 4);
                s16x8 v;
                v[0] = f2bf(f0.x); v[1] = f2bf(f0.y); v[2] = f2bf(f0.z); v[3] = f2bf(f0.w);
                v[4] = f2bf(f1.x); v[5] = f2bf(f1.y); v[6] = f2bf(f1.z); v[7] = f2bf(f1.w);
                *(s16x8*)&As[row * 64 + ((a_kg ^ (row & 7)) << 3)] = v;
            }
        }
        {
            const int rbase = k0 >> 1;
            #pragma unroll
            for (int i = 0; i < 4; ++i) {
                const int rg = b_rg0 + 2 * i;
                const int* qp = qw + (size_t)(rbase + rg * 4) * N_TOT + ocol;
                s16x8 v;
                #pragma unroll
                for (int rr = 0; rr < 4; ++rr) {
                    const int q = qp[(size_t)rr * N_TOT];
                    v[2 * rr]     = f2bf(fmaf((float)(q & 15), c0, c1));
                    v[2 * rr + 1] = f2bf(fmaf((float)((q >> 4) & 15), c0, c1));
                }
                *(s16x8*)&Bs[b_oloc * 64 + ((rg ^ (b_oloc & 7)) << 3)] = v;
            }
        }
        __syncthreads();
        #pragma unroll
        for (int ks = 0; ks < 2; ++ks) {
            const int slot = ks * 4 + lk;
            s16x8 a[4], b[4];
            #pragma unroll
            for (int mi = 0; mi < 4; ++mi) {
                const int row = wr * 64 + mi * 16 + lrow;
                a[mi] = *(const s16x8*)&As[row * 64 + ((slot ^ (row & 7)) << 3)];
            }
            #pragma unroll
            for (int ni = 0; ni < 4; ++ni) {
                const int row = wc * 64 + ni * 16 + lrow;
                b[ni] = *(const s16x8*)&Bs[row * 64 + ((slot ^ (row & 7)) << 3)];
            }
            #pragma unroll
            for (int mi = 0; mi < 4; ++mi)
                #pragma unroll
                for (int ni = 0; ni < 4; ++ni)
                    acc[mi][ni] = __builtin_amdgcn_mfma_f32_16x16x32_bf16(
                        a[mi], b[ni], acc[mi][ni], 0, 0, 0);
        }
        __syncthreads();
    }

    #pragma unroll
    for (int mi = 0; mi < 4; ++mi) {
        const int rg = m0 + wr * 64 + mi * 16 + lk * 4;
        #pragma unroll
        for (int ni = 0; ni < 4; ++ni) {
            const int cg = n0 + wc * 64 + ni * 16 + lrow;
            const float bs = bias[cg];
            #pragma unroll
            for (int j = 0; j < 4; ++j)
                out[(size_t)(rg + j) * N_TOT + cg] = acc[mi][ni][j] + bs;
        }
    }
}

extern "C" void kernel_launch(void* const* d_in, const int* in_sizes, int n_in,
                              void* d_out, int out_size, void* d_ws, size_t ws_size,
                              hipStream_t stream) {
    const float* x      = (const float*)d_in[0];
    const int*   qw     = (const int*)d_in[1];
    const float* scales = (const float*)d_in[2];
    const float* zeros  = (const float*)d_in[3];
    const float* bias   = (const float*)d_in[4];
    float* out = (float*)d_out;

    const size_t XQ_BYTES = (size_t)M_TOT * K_TOT;        // 32 MiB
    const size_t WQ_BYTES = (size_t)N_TOT * K_TOT;        // 16 MiB
    const size_t SX_BYTES = (size_t)M_TOT * 4;
    const size_t NEED = XQ_BYTES + WQ_BYTES + 2 * SX_BYTES;

    if (ws_size >= NEED) {
        char*  xq   = (char*)d_ws;
        char*  wqt  = (char*)d_ws + XQ_BYTES;
        float* sxv  = (float*)((char*)d_ws + XQ_BYTES + WQ_BYTES);
        float* sumv = sxv + M_TOT;

        hipLaunchKernelGGL(prep, dim3(M_TOT + 1024), dim3(256), 0, stream,
                           x, qw, xq, wqt, sxv, sumv);
        hipLaunchKernelGGL(gemm_i8, dim3(N_TOT / BN, M_TOT / BM), dim3(256), 0, stream,
                           xq, wqt, sxv, sumv, scales, zeros, bias, out);
    } else {
        hipLaunchKernelGGL(qlin_fused, dim3(N_TOT / 128, M_TOT / 128), dim3(256), 0, stream,
                           x, qw, scales, zeros, bias, out);
    }
}